// Round 12
// baseline (138.151 us; speedup 1.0000x reference)
//
#include <hip/hip_runtime.h>

typedef __attribute__((ext_vector_type(8))) short bf16x8;
typedef __attribute__((ext_vector_type(4))) float f32x4;

__device__ __forceinline__ unsigned short f2bf(float f) {
    unsigned int u = __builtin_bit_cast(unsigned int, f);
    unsigned int r = (u + 0x7FFFu + ((u >> 16) & 1u)) >> 16;
    return (unsigned short)r;
}
__device__ __forceinline__ unsigned int pkbf(float lo, float hi) {
    unsigned int ul = __builtin_bit_cast(unsigned int, lo) + 0x8000u;
    unsigned int uh = __builtin_bit_cast(unsigned int, hi) + 0x8000u;
    return (uh & 0xFFFF0000u) | (ul >> 16);
}
__device__ __forceinline__ float bf2f(unsigned short u) {
    unsigned int x = ((unsigned int)u) << 16;
    return __builtin_bit_cast(float, x);
}

__device__ __forceinline__ void gll16(const void* g, void* l) {
    __builtin_amdgcn_global_load_lds(
        (const __attribute__((address_space(1))) void*)g,
        (__attribute__((address_space(3))) void*)l, 16, 0, 0);
}

// ---------------------------------------------------------------------------
// kW: tiled transpose + fp32->bf16. src [b][R][C] f32 -> dstT [b][C][R] bf16.
// ---------------------------------------------------------------------------
__global__ __launch_bounds__(256) void transpose_cvt_kernel(
    const float* __restrict__ src, unsigned short* __restrict__ dstT,
    unsigned short* __restrict__ dstS, int R, int C)
{
    __shared__ float tile[64][65];
    const int b = blockIdx.z;
    const float* s = src + (size_t)b * R * C;
    const int r0 = blockIdx.x * 64, c0 = blockIdx.y * 64;
    const int t = threadIdx.x;
    const int r = t >> 2, cg = (t & 3) * 16;

    float v[16];
    const float4* p = reinterpret_cast<const float4*>(s + (size_t)(r0 + r) * C + c0 + cg);
#pragma unroll
    for (int i = 0; i < 4; ++i) {
        float4 q = p[i];
        v[4 * i + 0] = q.x; v[4 * i + 1] = q.y; v[4 * i + 2] = q.z; v[4 * i + 3] = q.w;
    }
#pragma unroll
    for (int i = 0; i < 16; ++i) tile[r][cg + i] = v[i];

    if (dstS) {
        unsigned int w[8];
#pragma unroll
        for (int i = 0; i < 8; ++i)
            w[i] = (unsigned)f2bf(v[2 * i]) | ((unsigned)f2bf(v[2 * i + 1]) << 16);
        unsigned int* d = reinterpret_cast<unsigned int*>(
            dstS + (size_t)b * R * C + (size_t)(r0 + r) * C + c0 + cg);
        *reinterpret_cast<uint4*>(d)     = make_uint4(w[0], w[1], w[2], w[3]);
        *reinterpret_cast<uint4*>(d + 4) = make_uint4(w[4], w[5], w[6], w[7]);
    }

    __syncthreads();

    const int cl = t >> 2, rg = (t & 3) * 16;
    unsigned int w[8];
#pragma unroll
    for (int i = 0; i < 8; ++i) {
        unsigned short lo = f2bf(tile[rg + 2 * i][cl]);
        unsigned short hi = f2bf(tile[rg + 2 * i + 1][cl]);
        w[i] = (unsigned)lo | ((unsigned)hi << 16);
    }
    unsigned int* d = reinterpret_cast<unsigned int*>(
        dstT + (size_t)b * R * C + (size_t)(c0 + cl) * R + r0 + rg);
    *reinterpret_cast<uint4*>(d)     = make_uint4(w[0], w[1], w[2], w[3]);
    *reinterpret_cast<uint4*>(d + 4) = make_uint4(w[4], w[5], w[6], w[7]);
}

// ---------------------------------------------------------------------------
// kPre: H = F@W1 + bias (bf16) and G^T = (F@W2)^T (bf16 [b][256][2048]).
// Unchanged (verified).
// ---------------------------------------------------------------------------
__global__ __launch_bounds__(256, 2) void kpre_gemm(
    const float* __restrict__ F, const unsigned short* __restrict__ Wt,
    const float* __restrict__ bias, unsigned short* __restrict__ H,
    unsigned short* __restrict__ Gt)
{
    __shared__ __align__(16) short Fb[64 * 256];   // 32KB
    __shared__ __align__(16) short Wb[256 * 64];   // 32KB (+ G^T scratch)

    const int tid = threadIdx.x;
    const int lane = tid & 63, wid = tid >> 6;
    const int lo = lane & 15, hi = lane >> 4;
    const int rb = blockIdx.x;
    const int batch = rb >> 5;
    const int mb = (rb & 31) * 64;
    const size_t m0g = (size_t)rb * 64;

    {
        const int frow = tid >> 2, fq = tid & 3;
        const float* fp = F + (m0g + frow) * 256 + fq * 64;
#pragma unroll
        for (int g = 0; g < 2; ++g) {
            float4 q[8];
#pragma unroll
            for (int i = 0; i < 8; ++i)
                q[i] = reinterpret_cast<const float4*>(fp)[g * 8 + i];
#pragma unroll
            for (int j = 0; j < 4; ++j) {
                unsigned int w0 = pkbf(q[2*j].x,   q[2*j].y);
                unsigned int w1 = pkbf(q[2*j].z,   q[2*j].w);
                unsigned int w2 = pkbf(q[2*j+1].x, q[2*j+1].y);
                unsigned int w3 = pkbf(q[2*j+1].z, q[2*j+1].w);
                int slot = fq * 8 + g * 4 + j;
                int off = frow * 256 + ((slot ^ (frow & 7)) << 3);
                *reinterpret_cast<uint4*>(&Fb[off]) = make_uint4(w0, w1, w2, w3);
            }
        }
    }

    f32x4 acc[4][4];

#pragma unroll
    for (int pass = 0; pass < 2; ++pass) {
#pragma unroll
        for (int m = 0; m < 4; ++m)
#pragma unroll
            for (int n = 0; n < 4; ++n) acc[m][n] = (f32x4){0.f, 0.f, 0.f, 0.f};

        for (int kt = 0; kt < 4; ++kt) {
            const int kbase = pass * 256 + kt * 64;
#pragma unroll
            for (int it = 0; it < 8; ++it) {
                int si = it * 256 + tid;
                int row = si >> 3, slot = si & 7;
                const unsigned short* g = Wt + (size_t)row * 512 + kbase + ((slot ^ (row & 7)) << 3);
                gll16(g, Wb + (size_t)si * 8);
            }
            __syncthreads();

#pragma unroll
            for (int kk = 0; kk < 2; ++kk) {
                bf16x8 af[4], bw[4];
#pragma unroll
                for (int m = 0; m < 4; ++m) {
                    int row = m * 16 + lo;
                    int slot = kt * 8 + kk * 4 + hi;
                    af[m] = *reinterpret_cast<const bf16x8*>(&Fb[row * 256 + ((slot ^ (row & 7)) << 3)]);
                }
#pragma unroll
                for (int n = 0; n < 4; ++n) {
                    int row = wid * 64 + n * 16 + lo;
                    bw[n] = *reinterpret_cast<const bf16x8*>(&Wb[row * 64 + (((kk * 4 + hi) ^ (row & 7)) << 3)]);
                }
#pragma unroll
                for (int m = 0; m < 4; ++m)
#pragma unroll
                    for (int n = 0; n < 4; ++n)
                        acc[m][n] = __builtin_amdgcn_mfma_f32_16x16x32_bf16(af[m], bw[n], acc[m][n], 0, 0, 0);
            }
            __syncthreads();
        }

        if (pass == 0) {
            float bv[4];
#pragma unroll
            for (int n = 0; n < 4; ++n) bv[n] = bias[wid * 64 + n * 16 + lo];
            unsigned short* Hb = H + m0g * 256;
#pragma unroll
            for (int m = 0; m < 4; ++m)
#pragma unroll
                for (int n = 0; n < 4; ++n)
#pragma unroll
                    for (int j = 0; j < 4; ++j) {
                        int row = m * 16 + hi * 4 + j;
                        int col = wid * 64 + n * 16 + lo;
                        Hb[(size_t)row * 256 + col] = f2bf(acc[m][n][j] + bv[n]);
                    }
        } else {
            short* T = Wb + wid * 4096;
#pragma unroll
            for (int m = 0; m < 4; ++m)
#pragma unroll
                for (int n = 0; n < 4; ++n)
#pragma unroll
                    for (int j = 0; j < 4; ++j) {
                        int gr = m * 16 + hi * 4 + j;
                        int gc = n * 16 + lo;
                        int slot = gr >> 3, e = gr & 7;
                        T[gc * 64 + ((slot ^ (gc & 7)) << 3) + e] = f2bf(acc[m][n][j]);
                    }
            unsigned short* Gb = Gt + ((size_t)batch * 256 + wid * 64) * 2048 + mb;
#pragma unroll
            for (int i = 0; i < 8; ++i) {
                int f = i * 8 + (lane >> 3);
                int s = lane & 7;
                bf16x8 v = *reinterpret_cast<const bf16x8*>(&T[f * 64 + ((s ^ (f & 7)) << 3)]);
                *reinterpret_cast<bf16x8*>(Gb + (size_t)f * 2048 + s * 8) = v;
            }
        }
    }
}

// ---------------------------------------------------------------------------
// kMain (R12): P[ks] = A[:, ks*1024:+1024] @ G — LEDGER-MINIMIZED.
// BM=256 halves Gt re-reads (2048/BM=8 per batch-half); split-K=2 keeps
// grid=256 (1 block/CU, 8 waves) with A and Gt columns read EXACTLY once.
// Ingest ledger: A 268 MB fp32 + Gt 134 MB = 402 MB (vs 586 in R5-R9) ->
// predicted ~64-73 µs at the measured ~6.3 TB/s per-CU ingest law.
// 512 thr, 8 waves 2x4, wave tile 128x64 (acc[8][4]); dbuf 128KB LDS;
// plain 1-sync-per-body 2-phase (schedule proven non-factor R4-R8).
// ---------------------------------------------------------------------------
__global__ __launch_bounds__(512) void kmain_gemm(
    const float* __restrict__ A, const unsigned short* __restrict__ Gt,
    unsigned short* __restrict__ P)
{
    __shared__ __align__(16) short Ab[2][256 * 64];   // 2 x 32 KB
    __shared__ __align__(16) short Bb[2][256 * 64];   // 2 x 32 KB

    const int tid = threadIdx.x;
    const int lane = tid & 63, wid = tid >> 6;
    const int wr = wid >> 2, wc = wid & 3;            // 2x4 -> wave tile 128x64
    const int lo = lane & 15, hi = lane >> 4;

    const int bid = blockIdx.x;
    const int wg = ((bid & 7) << 5) | (bid >> 3);     // bijective, 256 % 8 == 0
    const int batch = wg >> 4;                        // 2 batches per XCD
    const int ks    = (wg >> 3) & 1;
    const int mt    = wg & 7;

    const float* Abase = A + ((size_t)batch * 2048 + (size_t)mt * 256) * 2048 + (size_t)ks * 1024;
    const unsigned short* Gbase = Gt + (size_t)batch * 256 * 2048 + (size_t)ks * 1024;

    const int arow = tid >> 1;          // 0..255
    const int ac0  = (tid & 1) * 32;    // 32-float (128B) contiguous group

    f32x4 acc[8][4];
#pragma unroll
    for (int m = 0; m < 8; ++m)
#pragma unroll
        for (int n = 0; n < 4; ++n) acc[m][n] = (f32x4){0.f, 0.f, 0.f, 0.f};

    float4 qa[8];   // one body's A: 128B contiguous per thread
    auto loadA = [&](int k0) {
        const float4* p = reinterpret_cast<const float4*>(
            Abase + (size_t)arow * 2048 + k0 + ac0);
#pragma unroll
        for (int i = 0; i < 8; ++i) qa[i] = p[i];
    };
    auto writeA = [&](int buf) {
#pragma unroll
        for (int j = 0; j < 4; ++j) {
            uint4 w;
            w.x = pkbf(qa[2*j].x,   qa[2*j].y);
            w.y = pkbf(qa[2*j].z,   qa[2*j].w);
            w.z = pkbf(qa[2*j+1].x, qa[2*j+1].y);
            w.w = pkbf(qa[2*j+1].z, qa[2*j+1].w);
            int slot = (tid & 1) * 4 + j;
            int off = arow * 64 + ((slot ^ (arow & 7)) << 3);
            *reinterpret_cast<uint4*>(&Ab[buf][off]) = w;
        }
    };
    auto stageB = [&](int buf, int k0) {
#pragma unroll
        for (int it = 0; it < 4; ++it) {
            int si = it * 512 + tid;
            int row = si >> 3, slot = si & 7;
            const unsigned short* g = Gbase + (size_t)row * 2048 + k0 + ((slot ^ (row & 7)) << 3);
            gll16(g, &Bb[buf][(size_t)si * 8]);
        }
    };
    // process M in two halves of 4 fragments to limit live VGPRs
    auto compute = [&](int buf) {
#pragma unroll
        for (int kk = 0; kk < 2; ++kk) {
            bf16x8 bfv[4];
#pragma unroll
            for (int n = 0; n < 4; ++n) {
                int row = wc * 64 + n * 16 + lo;
                bfv[n] = *reinterpret_cast<const bf16x8*>(
                    &Bb[buf][row * 64 + (((kk * 4 + hi) ^ (row & 7)) << 3)]);
            }
#pragma unroll
            for (int mh = 0; mh < 2; ++mh) {
                bf16x8 af[4];
#pragma unroll
                for (int m = 0; m < 4; ++m) {
                    int row = wr * 128 + (mh * 4 + m) * 16 + lo;
                    af[m] = *reinterpret_cast<const bf16x8*>(
                        &Ab[buf][row * 64 + (((kk * 4 + hi) ^ (row & 7)) << 3)]);
                }
                __builtin_amdgcn_s_setprio(1);
#pragma unroll
                for (int m = 0; m < 4; ++m)
#pragma unroll
                    for (int n = 0; n < 4; ++n)
                        acc[mh * 4 + m][n] = __builtin_amdgcn_mfma_f32_16x16x32_bf16(
                            af[m], bfv[n], acc[mh * 4 + m][n], 0, 0, 0);
                __builtin_amdgcn_s_setprio(0);
            }
        }
    };

    // prologue: tile0 fully staged; tile1 issued (drains at body0's sync)
    loadA(0);
    stageB(0, 0);
    writeA(0);          // compiler waits qa(0) flats only
    __syncthreads();    // gll(0) + ds_writes drained
    loadA(64);          // qa(1)
    stageB(1, 64);      // gll(1), in flight through body 0

    for (int t = 0; t < 16; ++t) {
        const int cur = t & 1;
        compute(cur);
        if (t + 1 < 16) writeA(cur ^ 1);   // waits qa(t+1); Ab[nxt] free since sync(t-1)
        __syncthreads();                   // drains gll(t+1) + A ds_writes
        if (t + 2 < 16) {
            loadA((t + 2) * 64);           // qa(t+2): full body to land
            stageB(cur, (t + 2) * 64);     // gll(t+2) into freed buffer
        }
    }

    // epilogue -> bf16 partials P[ks]
    unsigned short* Pb = P + ((size_t)ks * 32768 + (size_t)batch * 2048 + (size_t)mt * 256) * 256;
#pragma unroll
    for (int m = 0; m < 8; ++m) {
#pragma unroll
        for (int n = 0; n < 4; ++n) {
            int col = wc * 64 + n * 16 + lo;
#pragma unroll
            for (int j = 0; j < 4; ++j) {
                int row = wr * 128 + m * 16 + hi * 4 + j;
                Pb[(size_t)row * 256 + col] = f2bf(acc[m][n][j]);
            }
        }
    }
}

// ---------------------------------------------------------------------------
// kRed: out = relu(P0 + P1 + H) (verified in R10).
// ---------------------------------------------------------------------------
__global__ __launch_bounds__(256) void kred_kernel(
    const unsigned short* __restrict__ P, const unsigned short* __restrict__ H,
    float* __restrict__ out)
{
    const long long n8 = (long long)32768 * 256 / 8;
    const long long p1 = (long long)32768 * 256;
    long long i = (long long)blockIdx.x * 256 + threadIdx.x;
    const long long stride = (long long)gridDim.x * 256;
    for (; i < n8; i += stride) {
        bf16x8 a = *reinterpret_cast<const bf16x8*>(&P[i * 8]);
        bf16x8 b = *reinterpret_cast<const bf16x8*>(&P[p1 + i * 8]);
        bf16x8 h = *reinterpret_cast<const bf16x8*>(&H[i * 8]);
        float4 o0, o1;
        float v;
        v = bf2f((unsigned short)a[0]) + bf2f((unsigned short)b[0]) + bf2f((unsigned short)h[0]); o0.x = fmaxf(v, 0.f);
        v = bf2f((unsigned short)a[1]) + bf2f((unsigned short)b[1]) + bf2f((unsigned short)h[1]); o0.y = fmaxf(v, 0.f);
        v = bf2f((unsigned short)a[2]) + bf2f((unsigned short)b[2]) + bf2f((unsigned short)h[2]); o0.z = fmaxf(v, 0.f);
        v = bf2f((unsigned short)a[3]) + bf2f((unsigned short)b[3]) + bf2f((unsigned short)h[3]); o0.w = fmaxf(v, 0.f);
        v = bf2f((unsigned short)a[4]) + bf2f((unsigned short)b[4]) + bf2f((unsigned short)h[4]); o1.x = fmaxf(v, 0.f);
        v = bf2f((unsigned short)a[5]) + bf2f((unsigned short)b[5]) + bf2f((unsigned short)h[5]); o1.y = fmaxf(v, 0.f);
        v = bf2f((unsigned short)a[6]) + bf2f((unsigned short)b[6]) + bf2f((unsigned short)h[6]); o1.z = fmaxf(v, 0.f);
        v = bf2f((unsigned short)a[7]) + bf2f((unsigned short)b[7]) + bf2f((unsigned short)h[7]); o1.w = fmaxf(v, 0.f);
        reinterpret_cast<float4*>(out + i * 8)[0] = o0;
        reinterpret_cast<float4*>(out + i * 8)[1] = o1;
    }
}

// ---------------------------------------------------------------------------
extern "C" void kernel_launch(void* const* d_in, const int* in_sizes, int n_in,
                              void* d_out, int out_size, void* d_ws, size_t ws_size,
                              hipStream_t stream) {
    const float* features = (const float*)d_in[0];   // [16][2048][256]
    const float* A        = (const float*)d_in[1];   // [16][2048][2048]
    const float* weight   = (const float*)d_in[2];   // [512][256]
    const float* bias     = (const float*)d_in[3];   // [256]
    float* out = (float*)d_out;

    const size_t WT_B = (size_t)256 * 512 * 2;             // 256 KB
    const size_t H_B  = (size_t)32768 * 256 * 2;           // 16.78 MB
    const size_t GT_B = (size_t)16 * 256 * 2048 * 2;       // 16.78 MB
    const size_t P_B  = (size_t)2 * 32768 * 256 * 2;       // 33.55 MB
    if (ws_size < WT_B + H_B + GT_B + P_B) return;

    char* ws = (char*)d_ws;
    unsigned short* Wt = (unsigned short*)ws;
    unsigned short* H  = (unsigned short*)(ws + WT_B);
    unsigned short* Gt = (unsigned short*)(ws + WT_B + H_B);
    unsigned short* P  = (unsigned short*)(ws + WT_B + H_B + GT_B);

    dim3 gW(512 / 64, 256 / 64, 1);
    transpose_cvt_kernel<<<gW, 256, 0, stream>>>(weight, Wt, nullptr, 512, 256);

    kpre_gemm<<<512, 256, 0, stream>>>(features, Wt, bias, H, Gt);

    kmain_gemm<<<256, 512, 0, stream>>>(A, Gt, P);

    kred_kernel<<<2048, 256, 0, stream>>>(P, H, out);
}

// Round 14
// 117.005 us; speedup vs baseline: 1.1807x; 1.1807x over previous
//
#include <hip/hip_runtime.h>

typedef __attribute__((ext_vector_type(8))) short bf16x8;
typedef __attribute__((ext_vector_type(4))) float f32x4;

__device__ __forceinline__ unsigned short f2bf(float f) {
    unsigned int u = __builtin_bit_cast(unsigned int, f);
    unsigned int r = (u + 0x7FFFu + ((u >> 16) & 1u)) >> 16;
    return (unsigned short)r;
}
__device__ __forceinline__ unsigned int pkbf(float lo, float hi) {
    unsigned int ul = __builtin_bit_cast(unsigned int, lo) + 0x8000u;
    unsigned int uh = __builtin_bit_cast(unsigned int, hi) + 0x8000u;
    return (uh & 0xFFFF0000u) | (ul >> 16);
}
__device__ __forceinline__ float bf2f(unsigned short u) {
    unsigned int x = ((unsigned int)u) << 16;
    return __builtin_bit_cast(float, x);
}

__device__ __forceinline__ void gll16(const void* g, void* l) {
    __builtin_amdgcn_global_load_lds(
        (const __attribute__((address_space(1))) void*)g,
        (__attribute__((address_space(3))) void*)l, 16, 0, 0);
}

// ---------------------------------------------------------------------------
// kW: tiled transpose + fp32->bf16. src [b][R][C] f32 -> dstT [b][C][R] bf16.
// ---------------------------------------------------------------------------
__global__ __launch_bounds__(256) void transpose_cvt_kernel(
    const float* __restrict__ src, unsigned short* __restrict__ dstT,
    unsigned short* __restrict__ dstS, int R, int C)
{
    __shared__ float tile[64][65];
    const int b = blockIdx.z;
    const float* s = src + (size_t)b * R * C;
    const int r0 = blockIdx.x * 64, c0 = blockIdx.y * 64;
    const int t = threadIdx.x;
    const int r = t >> 2, cg = (t & 3) * 16;

    float v[16];
    const float4* p = reinterpret_cast<const float4*>(s + (size_t)(r0 + r) * C + c0 + cg);
#pragma unroll
    for (int i = 0; i < 4; ++i) {
        float4 q = p[i];
        v[4 * i + 0] = q.x; v[4 * i + 1] = q.y; v[4 * i + 2] = q.z; v[4 * i + 3] = q.w;
    }
#pragma unroll
    for (int i = 0; i < 16; ++i) tile[r][cg + i] = v[i];

    if (dstS) {
        unsigned int w[8];
#pragma unroll
        for (int i = 0; i < 8; ++i)
            w[i] = (unsigned)f2bf(v[2 * i]) | ((unsigned)f2bf(v[2 * i + 1]) << 16);
        unsigned int* d = reinterpret_cast<unsigned int*>(
            dstS + (size_t)b * R * C + (size_t)(r0 + r) * C + c0 + cg);
        *reinterpret_cast<uint4*>(d)     = make_uint4(w[0], w[1], w[2], w[3]);
        *reinterpret_cast<uint4*>(d + 4) = make_uint4(w[4], w[5], w[6], w[7]);
    }

    __syncthreads();

    const int cl = t >> 2, rg = (t & 3) * 16;
    unsigned int w[8];
#pragma unroll
    for (int i = 0; i < 8; ++i) {
        unsigned short lo = f2bf(tile[rg + 2 * i][cl]);
        unsigned short hi = f2bf(tile[rg + 2 * i + 1][cl]);
        w[i] = (unsigned)lo | ((unsigned)hi << 16);
    }
    unsigned int* d = reinterpret_cast<unsigned int*>(
        dstT + (size_t)b * R * C + (size_t)(c0 + cl) * R + r0 + rg);
    *reinterpret_cast<uint4*>(d)     = make_uint4(w[0], w[1], w[2], w[3]);
    *reinterpret_cast<uint4*>(d + 4) = make_uint4(w[4], w[5], w[6], w[7]);
}

// ---------------------------------------------------------------------------
// kPre: H = F@W1 + bias (bf16) and G^T = (F@W2)^T (bf16 [b][256][2048]).
// Unchanged (verified).
// ---------------------------------------------------------------------------
__global__ __launch_bounds__(256, 2) void kpre_gemm(
    const float* __restrict__ F, const unsigned short* __restrict__ Wt,
    const float* __restrict__ bias, unsigned short* __restrict__ H,
    unsigned short* __restrict__ Gt)
{
    __shared__ __align__(16) short Fb[64 * 256];   // 32KB
    __shared__ __align__(16) short Wb[256 * 64];   // 32KB (+ G^T scratch)

    const int tid = threadIdx.x;
    const int lane = tid & 63, wid = tid >> 6;
    const int lo = lane & 15, hi = lane >> 4;
    const int rb = blockIdx.x;
    const int batch = rb >> 5;
    const int mb = (rb & 31) * 64;
    const size_t m0g = (size_t)rb * 64;

    {
        const int frow = tid >> 2, fq = tid & 3;
        const float* fp = F + (m0g + frow) * 256 + fq * 64;
#pragma unroll
        for (int g = 0; g < 2; ++g) {
            float4 q[8];
#pragma unroll
            for (int i = 0; i < 8; ++i)
                q[i] = reinterpret_cast<const float4*>(fp)[g * 8 + i];
#pragma unroll
            for (int j = 0; j < 4; ++j) {
                unsigned int w0 = pkbf(q[2*j].x,   q[2*j].y);
                unsigned int w1 = pkbf(q[2*j].z,   q[2*j].w);
                unsigned int w2 = pkbf(q[2*j+1].x, q[2*j+1].y);
                unsigned int w3 = pkbf(q[2*j+1].z, q[2*j+1].w);
                int slot = fq * 8 + g * 4 + j;
                int off = frow * 256 + ((slot ^ (frow & 7)) << 3);
                *reinterpret_cast<uint4*>(&Fb[off]) = make_uint4(w0, w1, w2, w3);
            }
        }
    }

    f32x4 acc[4][4];

#pragma unroll
    for (int pass = 0; pass < 2; ++pass) {
#pragma unroll
        for (int m = 0; m < 4; ++m)
#pragma unroll
            for (int n = 0; n < 4; ++n) acc[m][n] = (f32x4){0.f, 0.f, 0.f, 0.f};

        for (int kt = 0; kt < 4; ++kt) {
            const int kbase = pass * 256 + kt * 64;
#pragma unroll
            for (int it = 0; it < 8; ++it) {
                int si = it * 256 + tid;
                int row = si >> 3, slot = si & 7;
                const unsigned short* g = Wt + (size_t)row * 512 + kbase + ((slot ^ (row & 7)) << 3);
                gll16(g, Wb + (size_t)si * 8);
            }
            __syncthreads();

#pragma unroll
            for (int kk = 0; kk < 2; ++kk) {
                bf16x8 af[4], bw[4];
#pragma unroll
                for (int m = 0; m < 4; ++m) {
                    int row = m * 16 + lo;
                    int slot = kt * 8 + kk * 4 + hi;
                    af[m] = *reinterpret_cast<const bf16x8*>(&Fb[row * 256 + ((slot ^ (row & 7)) << 3)]);
                }
#pragma unroll
                for (int n = 0; n < 4; ++n) {
                    int row = wid * 64 + n * 16 + lo;
                    bw[n] = *reinterpret_cast<const bf16x8*>(&Wb[row * 64 + (((kk * 4 + hi) ^ (row & 7)) << 3)]);
                }
#pragma unroll
                for (int m = 0; m < 4; ++m)
#pragma unroll
                    for (int n = 0; n < 4; ++n)
                        acc[m][n] = __builtin_amdgcn_mfma_f32_16x16x32_bf16(af[m], bw[n], acc[m][n], 0, 0, 0);
            }
            __syncthreads();
        }

        if (pass == 0) {
            float bv[4];
#pragma unroll
            for (int n = 0; n < 4; ++n) bv[n] = bias[wid * 64 + n * 16 + lo];
            unsigned short* Hb = H + m0g * 256;
#pragma unroll
            for (int m = 0; m < 4; ++m)
#pragma unroll
                for (int n = 0; n < 4; ++n)
#pragma unroll
                    for (int j = 0; j < 4; ++j) {
                        int row = m * 16 + hi * 4 + j;
                        int col = wid * 64 + n * 16 + lo;
                        Hb[(size_t)row * 256 + col] = f2bf(acc[m][n][j] + bv[n]);
                    }
        } else {
            short* T = Wb + wid * 4096;
#pragma unroll
            for (int m = 0; m < 4; ++m)
#pragma unroll
                for (int n = 0; n < 4; ++n)
#pragma unroll
                    for (int j = 0; j < 4; ++j) {
                        int gr = m * 16 + hi * 4 + j;
                        int gc = n * 16 + lo;
                        int slot = gr >> 3, e = gr & 7;
                        T[gc * 64 + ((slot ^ (gc & 7)) << 3) + e] = f2bf(acc[m][n][j]);
                    }
            unsigned short* Gb = Gt + ((size_t)batch * 256 + wid * 64) * 2048 + mb;
#pragma unroll
            for (int i = 0; i < 8; ++i) {
                int f = i * 8 + (lane >> 3);
                int s = lane & 7;
                bf16x8 v = *reinterpret_cast<const bf16x8*>(&T[f * 64 + ((s ^ (f & 7)) << 3)]);
                *reinterpret_cast<bf16x8*>(Gb + (size_t)f * 2048 + s * 8) = v;
            }
        }
    }
}

// ---------------------------------------------------------------------------
// kMain (R14 = R13 fixed): out = relu(H + A @ G). EXACT R7 structure with ONE
// change: A loads NONTEMPORAL (via ext_vector f32x4 — HIP_vector_type float4
// is rejected by the builtin) + nt stores for out. Mechanism: stream-once A
// at 2x everyone's byte rate evicts the 1MB/batch Gt panel from the 4MB XCD
// L2, turning Gt's 268MB of re-reads into misses that saturate the per-CU
// miss-concurrency budget (~25GB/s/CU). nt-A keeps Gt L2-hot.
// BM=128 BN=256 BK=64, 8 waves (2x4), 96KB dbuf LDS, counted-vmcnt pipeline.
// ---------------------------------------------------------------------------
__global__ __launch_bounds__(512, 2) void kmain_gemm(
    const float* __restrict__ A, const unsigned short* __restrict__ Gt,
    const unsigned short* __restrict__ H, float* __restrict__ out)
{
    __shared__ __align__(16) short Ab[2][128 * 64];   // 2 x 16KB
    __shared__ __align__(16) short Bb[2][256 * 64];   // 2 x 32KB

    const int tid = threadIdx.x;
    const int lane = tid & 63, wid = tid >> 6;
    const int wr = wid >> 2, wc = wid & 3;
    const int lo = lane & 15, hi = lane >> 4;

    const int bid = blockIdx.x;
    const int wg = ((bid & 7) << 5) | (bid >> 3);   // bijective, 256 % 8 == 0
    const int batch = wg >> 4;
    const int mt    = wg & 15;

    const float* Abase = A + ((size_t)batch * 2048 + (size_t)mt * 128) * 2048;
    const unsigned short* Gbase = Gt + (size_t)batch * 256 * 2048;

    const int arow = tid >> 2;    // 0..127
    const int acg  = tid & 3;     // 16B sub-column within the 64B row-chunk

    f32x4 acc[4][4];
#pragma unroll
    for (int m = 0; m < 4; ++m)
#pragma unroll
        for (int n = 0; n < 4; ++n) acc[m][n] = (f32x4){0.f, 0.f, 0.f, 0.f};

    f32x4 qa0[4], qa1[4];   // two named prefetch sets (rule #20)

    // coalesced + NONTEMPORAL: instr i covers a dense 64B sector per 4 lanes,
    // lines not allocated in L2/L3 (stream-once data). ext_vector type is
    // accepted by __builtin_nontemporal_load.
    auto loadA = [&](f32x4* q, int k0) {
        const f32x4* p4 = reinterpret_cast<const f32x4*>(
            Abase + (size_t)arow * 2048 + k0);
#pragma unroll
        for (int i = 0; i < 4; ++i)
            q[i] = __builtin_nontemporal_load(&p4[acg + 4 * i]);
    };
    auto writeA = [&](int buf, const f32x4* q) {
#pragma unroll
        for (int i = 0; i < 4; ++i) {
            uint2 w;
            w.x = pkbf(q[i][0], q[i][1]);
            w.y = pkbf(q[i][2], q[i][3]);
            int s = 2 * i + (acg >> 1);
            int off = arow * 64 + ((s ^ (arow & 7)) << 3) + (acg & 1) * 4;
            *reinterpret_cast<uint2*>(&Ab[buf][off]) = w;
        }
    };
    auto stageB = [&](int buf, int k0) {
#pragma unroll
        for (int it = 0; it < 4; ++it) {
            int si = it * 512 + tid;
            int row = si >> 3, slot = si & 7;
            const unsigned short* g = Gbase + (size_t)row * 2048 + k0 + ((slot ^ (row & 7)) << 3);
            gll16(g, &Bb[buf][(size_t)si * 8]);
        }
    };
    auto compute = [&](int buf) {
#pragma unroll
        for (int kk = 0; kk < 2; ++kk) {
            bf16x8 af[4], bfv[4];
#pragma unroll
            for (int m = 0; m < 4; ++m) {
                int row = wr * 64 + m * 16 + lo;
                af[m] = *reinterpret_cast<const bf16x8*>(
                    &Ab[buf][row * 64 + (((kk * 4 + hi) ^ (row & 7)) << 3)]);
            }
#pragma unroll
            for (int n = 0; n < 4; ++n) {
                int row = wc * 64 + n * 16 + lo;
                bfv[n] = *reinterpret_cast<const bf16x8*>(
                    &Bb[buf][row * 64 + (((kk * 4 + hi) ^ (row & 7)) << 3)]);
            }
            __builtin_amdgcn_s_setprio(1);
#pragma unroll
            for (int m = 0; m < 4; ++m)
#pragma unroll
                for (int n = 0; n < 4; ++n)
                    acc[m][n] = __builtin_amdgcn_mfma_f32_16x16x32_bf16(af[m], bfv[n], acc[m][n], 0, 0, 0);
            __builtin_amdgcn_s_setprio(0);
        }
    };

    // ---- prologue ----
    loadA(qa0, 0);
    stageB(0, 0);
    writeA(0, qa0);
    loadA(qa1, 64);
    asm volatile("s_waitcnt vmcnt(4) lgkmcnt(0)" ::: "memory");
    __builtin_amdgcn_s_barrier();
    asm volatile("" ::: "memory");
    stageB(1, 64);

    // ---- steady: bodies t = 0..29, paired even/odd ----
    for (int tt = 0; tt < 15; ++tt) {
        const int t0 = tt * 2;
        writeA(1, qa1);
        loadA(qa0, (t0 + 2) * 64);
        compute(0);
        asm volatile("s_waitcnt vmcnt(4) lgkmcnt(0)" ::: "memory");
        __builtin_amdgcn_s_barrier();
        asm volatile("" ::: "memory");
        stageB(0, (t0 + 2) * 64);
        writeA(0, qa0);
        loadA(qa1, (t0 + 3) * 64);
        compute(1);
        asm volatile("s_waitcnt vmcnt(4) lgkmcnt(0)" ::: "memory");
        __builtin_amdgcn_s_barrier();
        asm volatile("" ::: "memory");
        stageB(1, (t0 + 3) * 64);
    }
    // ---- tail ----
    writeA(1, qa1);
    compute(0);
    asm volatile("s_waitcnt vmcnt(0) lgkmcnt(0)" ::: "memory");
    __builtin_amdgcn_s_barrier();
    asm volatile("" ::: "memory");
    compute(1);

    // ---- epilogue: out = relu(acc + H), nt stores ----
    const size_t rowbase = (size_t)batch * 2048 + (size_t)mt * 128;
    const unsigned short* Hb = H + rowbase * 256;
    float* obase = out + rowbase * 256;
#pragma unroll
    for (int m = 0; m < 4; ++m) {
#pragma unroll
        for (int n = 0; n < 4; ++n) {
            int col = wc * 64 + n * 16 + lo;
#pragma unroll
            for (int j = 0; j < 4; ++j) {
                int row = wr * 64 + m * 16 + hi * 4 + j;
                float v = acc[m][n][j] + bf2f(Hb[(size_t)row * 256 + col]);
                __builtin_nontemporal_store(fmaxf(v, 0.f), &obase[(size_t)row * 256 + col]);
            }
        }
    }
}

// ---------------------------------------------------------------------------
extern "C" void kernel_launch(void* const* d_in, const int* in_sizes, int n_in,
                              void* d_out, int out_size, void* d_ws, size_t ws_size,
                              hipStream_t stream) {
    const float* features = (const float*)d_in[0];   // [16][2048][256]
    const float* A        = (const float*)d_in[1];   // [16][2048][2048]
    const float* weight   = (const float*)d_in[2];   // [512][256]
    const float* bias     = (const float*)d_in[3];   // [256]
    float* out = (float*)d_out;

    const size_t WT_B = (size_t)256 * 512 * 2;             // 256 KB
    const size_t H_B  = (size_t)32768 * 256 * 2;           // 16.78 MB
    const size_t GT_B = (size_t)16 * 256 * 2048 * 2;       // 16.78 MB
    if (ws_size < WT_B + H_B + GT_B) return;

    char* ws = (char*)d_ws;
    unsigned short* Wt = (unsigned short*)ws;
    unsigned short* H  = (unsigned short*)(ws + WT_B);
    unsigned short* Gt = (unsigned short*)(ws + WT_B + H_B);

    dim3 gW(512 / 64, 256 / 64, 1);
    transpose_cvt_kernel<<<gW, 256, 0, stream>>>(weight, Wt, nullptr, 512, 256);

    kpre_gemm<<<512, 256, 0, stream>>>(features, Wt, bias, H, Gt);

    kmain_gemm<<<256, 512, 0, stream>>>(A, Gt, H, out);
}